// Round 6
// baseline (440.018 us; speedup 1.0000x reference)
//
#include <hip/hip_runtime.h>
#include <hip/hip_bf16.h>

#define HH 448
#define WW 160
#define NPIX (HH*WW)
#define BCOL 80          // columns per block (2 blocks per h)

typedef unsigned long long u64;

__device__ __forceinline__ float leaky(float v) { return v >= 0.f ? v : 0.01f * v; }

__device__ __forceinline__ u64 packKey(float m, int r) {
    unsigned u = __float_as_uint(m);
    u = (u & 0x80000000u) ? ~u : (u | 0x80000000u);   // monotone f32 -> u32
    return ((u64)u << 32) | (unsigned)(255 - r);       // ties -> lowest idx
}

// act: logical (w, c) -> phys float idx. Row = 128 floats (32 f4 blocks);
// phys block = (c/4) ^ (w & 7)  -> gemm reads (fixed c, w per-lane) span all 8 bank-quads.
__device__ __forceinline__ int actIdx(int w, int c) {
    return (w << 7) + ((((c >> 2) ^ (w & 7))) << 2) + (c & 3);
}

// Tile: 8 rows x 5 cols per thread, K=128.
// x: 5 ds_read_b128 per cb (2-addr/bank-quad + 4-way broadcast = free).
// W: 8 global_load_dwordx4 per cb from registers-stream (4 distinct 128B lines/instr,
//    lines fully consumed across cb-unroll; L1/L2-resident).
// FMA order: cb ascending, .x.y.z.w — bitwise-matches all verified rounds.
__device__ __forceinline__ void gemmVW(const float* actf, const float* __restrict__ Wg,
                                       const int colb[5], const int colk[5], float acc[8][5])
{
    const float4* a4 = reinterpret_cast<const float4*>(actf);
    const float4* w4 = reinterpret_cast<const float4*>(Wg);
#pragma unroll
    for (int a = 0; a < 8; ++a)
#pragma unroll
        for (int k = 0; k < 5; ++k) acc[a][k] = 0.f;

#pragma unroll 2
    for (int cb = 0; cb < 32; ++cb) {
        float4 wv[8];
#pragma unroll
        for (int a = 0; a < 8; ++a) wv[a] = w4[a * 32 + cb];
        float4 xv[5];
#pragma unroll
        for (int k = 0; k < 5; ++k) xv[k] = a4[colb[k] + (cb ^ colk[k])];
#pragma unroll
        for (int a = 0; a < 8; ++a)
#pragma unroll
            for (int k = 0; k < 5; ++k) {
                acc[a][k] = fmaf(wv[a].x, xv[k].x, acc[a][k]);
                acc[a][k] = fmaf(wv[a].y, xv[k].y, acc[a][k]);
                acc[a][k] = fmaf(wv[a].z, xv[k].z, acc[a][k]);
                acc[a][k] = fmaf(wv[a].w, xv[k].w, acc[a][k]);
            }
    }
}

__global__ __launch_bounds__(256, 3) void kA(
    const float* __restrict__ x_in,
    const float* __restrict__ Wcl1, const float* __restrict__ bcl1,
    const float* __restrict__ Wcl2, const float* __restrict__ bcl2,
    const float* __restrict__ Wcl3, const float* __restrict__ bcl3,
    const float* __restrict__ Wcl4, const float* __restrict__ bcl4,
    const float* __restrict__ Wreg1, const float* __restrict__ breg1,
    __hip_bfloat16* __restrict__ xr, int* __restrict__ ind, float* __restrict__ out)
{
    __shared__ float actf[BCOL * 128];   // 40 KB swizzled [w][c] activations (in-place)
    __shared__ u64 argb[BCOL];

    // bid -> (h, half): sibling halves of one h are 8 apart -> same XCD (L2 weight share)
    const int bid = blockIdx.x;
    const int h = ((bid >> 4) << 3) | (bid & 7);
    const int w0 = ((bid >> 3) & 1) * BCOL;

    const int t = threadIdx.x;
    const int rg = t >> 4;        // 0..15 row group (8 rows)
    const int cg = t & 15;        // 0..15 col group (cols cg+16k, k<5)
    const int rbase = rg << 3;

    int colb[5], colk[5];
#pragma unroll
    for (int k = 0; k < 5; ++k) { const int wl = cg + (k << 4); colb[k] = wl << 5; colk[k] = wl & 7; }

    if (t < BCOL) argb[t] = 0ull;

    // ---- stage x: x_in[c][h][w0..w0+79] -> act (transpose + swizzle) ----
    {
        const float4* xg = reinterpret_cast<const float4*>(x_in);
#pragma unroll
        for (int k = 0; k < 10; ++k) {
            const int fi = t + (k << 8);          // 0..2559 float4s
            const int c = fi / 20, wq = fi - c * 20;
            const float4 v = xg[c * 17920 + h * 40 + (w0 >> 2) + wq];
            const int wl = wq << 2;
            actf[actIdx(wl + 0, c)] = v.x;
            actf[actIdx(wl + 1, c)] = v.y;
            actf[actIdx(wl + 2, c)] = v.z;
            actf[actIdx(wl + 3, c)] = v.w;
        }
    }
    __syncthreads();

    // ---- reg1: 256 rows in 2 passes, bf16 out to xr; no act writes ----
    {
        const float* W1 = Wreg1 + (size_t)h * 32768;
        const float* b1 = breg1 + h * 256;
#pragma unroll 1
        for (int p = 0; p < 2; ++p) {
            const int roff = (p << 7) + rbase;
            float acc[8][5];
            gemmVW(actf, W1 + roff * 128, colb, colk, acc);
            float bb[8];
#pragma unroll
            for (int a = 0; a < 8; ++a) bb[a] = b1[roff + a];
#pragma unroll
            for (int k = 0; k < 5; ++k) {
                const int w = w0 + cg + (k << 4);
                alignas(16) unsigned short us[8];
#pragma unroll
                for (int a = 0; a < 8; ++a) {
                    __hip_bfloat16 bv = __float2bfloat16(leaky(acc[a][k] + bb[a]));
                    us[a] = *reinterpret_cast<const unsigned short*>(&bv);
                }
                *reinterpret_cast<uint4*>(xr + (((size_t)(h * WW + w)) << 8) + roff) =
                    *reinterpret_cast<const uint4*>(us);
            }
        }
    }

    // ---- cl1..cl3: in-place act update ----
#pragma unroll 1
    for (int L = 0; L < 3; ++L) {
        const float* W = (L == 0) ? Wcl1 + (size_t)h * 16384
                       : (L == 1) ? Wcl2 + (size_t)h * 16384
                                  : Wcl3 + (size_t)h * 16384;
        const float* b = (L == 0) ? bcl1 + (h << 7)
                       : (L == 1) ? bcl2 + (h << 7)
                                  : bcl3 + (h << 7);
        float acc[8][5];
        gemmVW(actf, W + rbase * 128, colb, colk, acc);
        float bb[8];
#pragma unroll
        for (int a = 0; a < 8; ++a) bb[a] = b[rbase + a];
        __syncthreads();               // all act reads done
#pragma unroll
        for (int k = 0; k < 5; ++k) {
            const int wl = cg + (k << 4);
            float4 lo, hi;
            lo.x = leaky(acc[0][k] + bb[0]); lo.y = leaky(acc[1][k] + bb[1]);
            lo.z = leaky(acc[2][k] + bb[2]); lo.w = leaky(acc[3][k] + bb[3]);
            hi.x = leaky(acc[4][k] + bb[4]); hi.y = leaky(acc[5][k] + bb[5]);
            hi.z = leaky(acc[6][k] + bb[6]); hi.w = leaky(acc[7][k] + bb[7]);
            float4* row = reinterpret_cast<float4*>(actf) + (wl << 5);
            row[((rbase >> 2)    ) ^ (wl & 7)] = lo;
            row[((rbase >> 2) + 1) ^ (wl & 7)] = hi;
        }
        __syncthreads();
    }

    // ---- cl4: 256 class rows in 2 passes; argmax only (logits never stored) ----
    {
        const float* W4 = Wcl4 + (size_t)h * 32896;
        const float* b4 = bcl4 + h * 257;
        float mv[5]; int mr[5];
#pragma unroll
        for (int k = 0; k < 5; ++k) { mv[k] = -3.4e38f; mr[k] = 0; }
#pragma unroll 1
        for (int p = 0; p < 2; ++p) {
            const int roff = (p << 7) + rbase;
            float acc[8][5];
            gemmVW(actf, W4 + roff * 128, colb, colk, acc);
            float bb[8];
#pragma unroll
            for (int a = 0; a < 8; ++a) bb[a] = b4[roff + a];
#pragma unroll
            for (int k = 0; k < 5; ++k)
#pragma unroll
                for (int a = 0; a < 8; ++a) {
                    const float v = acc[a][k] + bb[a];   // rows ascending per thread
                    if (v > mv[k]) { mv[k] = v; mr[k] = roff + a; }
                }
        }
#pragma unroll
        for (int k = 0; k < 5; ++k)
            atomicMax(&argb[cg + (k << 4)], packKey(mv[k], mr[k]));
    }
    __syncthreads();

    // ---- finalize: ind + mask row (act still holds cl3 output) ----
    if (t < BCOL) {
        const u64 k = argb[t];
        ind[h * WW + w0 + t] = 255 - (int)(k & 0xFFu);
        const float* Wm = Wcl4 + (size_t)h * 32896 + 32768;   // class row 256
        float accm = 0.f;
        const float4* arow = reinterpret_cast<const float4*>(actf) + (t << 5);
#pragma unroll 4
        for (int cb = 0; cb < 32; ++cb) {
            const float4 xv = arow[cb ^ (t & 7)];
            accm = fmaf(Wm[cb * 4 + 0], xv.x, accm);
            accm = fmaf(Wm[cb * 4 + 1], xv.y, accm);
            accm = fmaf(Wm[cb * 4 + 2], xv.z, accm);
            accm = fmaf(Wm[cb * 4 + 3], xv.w, accm);
        }
        out[NPIX + h * WW + w0 + t] = leaky(accm + bcl4[h * 257 + 256]);
    }
}

__global__ __launch_bounds__(256) void kB(
    const __hip_bfloat16* __restrict__ xr, const int* __restrict__ ind,
    const float* __restrict__ Wcm2, const float* __restrict__ bcm2,
    const float* __restrict__ Wcm3, const float* __restrict__ bcm3,
    float* __restrict__ out)
{
    const int gwave = (int)((blockIdx.x * blockDim.x + threadIdx.x) >> 6);
    const int lane = threadIdx.x & 63;
    const int nwave = (int)(gridDim.x * (blockDim.x >> 6));

    for (int n = gwave; n < NPIX; n += nwave) {
        const int h_o = n % HH, w_o = n / HH;   // xr source & output position (w-major flat)
        const int h_i = n / WW, w_i = n % WW;   // index-gather position (h-major flat)
        const int ig = ind[h_i * WW + w_i];
        const int sc = (ig >> 4) + (h_i << 4);
        const int rr = ig + (h_i << 8);

        const __hip_bfloat16* xp = xr + (size_t)(h_o * WW + w_o) * 256;
        const float* Wp = Wcm2 + (size_t)sc * 2048;

        float acc[8];
#pragma unroll
        for (int o = 0; o < 8; ++o) acc[o] = 0.f;

        const int c0 = lane * 4;
        const ushort4 xv4 = *(const ushort4*)((const unsigned short*)xp + c0);
        float xf[4];
        xf[0] = __uint_as_float((unsigned int)xv4.x << 16);
        xf[1] = __uint_as_float((unsigned int)xv4.y << 16);
        xf[2] = __uint_as_float((unsigned int)xv4.z << 16);
        xf[3] = __uint_as_float((unsigned int)xv4.w << 16);

#pragma unroll
        for (int i = 0; i < 4; ++i) {
            const float4* wrow = (const float4*)&Wp[(c0 + i) * 8];
            const float4 wa = wrow[0];
            const float4 wb_ = wrow[1];
            const float x = xf[i];
            acc[0] += x * wa.x;  acc[1] += x * wa.y;  acc[2] += x * wa.z;  acc[3] += x * wa.w;
            acc[4] += x * wb_.x; acc[5] += x * wb_.y; acc[6] += x * wb_.z; acc[7] += x * wb_.w;
        }
#pragma unroll
        for (int o = 0; o < 8; ++o) {
            float v = acc[o];
#pragma unroll
            for (int d = 32; d > 0; d >>= 1) v += __shfl_xor(v, d, 64);
            acc[o] = v;
        }
        float r = bcm3[rr];
        const float* b2 = bcm2 + (size_t)sc * 8;
        const float* w3 = Wcm3 + (size_t)rr * 8;
#pragma unroll
        for (int o = 0; o < 8; ++o) {
            const float y = leaky(acc[o] + b2[o]);
            r += y * w3[o];
        }
        if (lane == 0) {
            const float iv = (float)ind[h_o * WW + w_o];
            out[h_o * WW + w_o] = (iv + r) * (1.0f / 256.0f);
        }
    }
}

extern "C" void kernel_launch(void* const* d_in, const int* in_sizes, int n_in,
                              void* d_out, int out_size, void* d_ws, size_t ws_size,
                              hipStream_t stream)
{
    const float* x_in  = (const float*)d_in[0];
    const float* Wcl1  = (const float*)d_in[1];
    const float* bcl1  = (const float*)d_in[2];
    const float* Wcl2  = (const float*)d_in[3];
    const float* bcl2  = (const float*)d_in[4];
    const float* Wcl3  = (const float*)d_in[5];
    const float* bcl3  = (const float*)d_in[6];
    const float* Wcl4  = (const float*)d_in[7];
    const float* bcl4  = (const float*)d_in[8];
    const float* Wreg1 = (const float*)d_in[9];
    const float* breg1 = (const float*)d_in[10];
    const float* Wcm2  = (const float*)d_in[11];
    const float* bcm2  = (const float*)d_in[12];
    const float* Wcm3  = (const float*)d_in[13];
    const float* bcm3  = (const float*)d_in[14];

    float* out = (float*)d_out;

    // workspace: x_r as bf16 [448][160][256], then ind int32 [448*160]
    __hip_bfloat16* xr = (__hip_bfloat16*)d_ws;
    int* ind = (int*)((char*)d_ws + (size_t)NPIX * 256 * sizeof(__hip_bfloat16));

    kA<<<dim3(HH * 2), dim3(256), 0, stream>>>(x_in, Wcl1, bcl1, Wcl2, bcl2, Wcl3, bcl3,
                                               Wcl4, bcl4, Wreg1, breg1, xr, ind, out);
    kB<<<dim3(1792), dim3(256), 0, stream>>>(xr, ind, Wcm2, bcm2, Wcm3, bcm3, out);
}

// Round 8
// 188.320 us; speedup vs baseline: 2.3365x; 2.3365x over previous
//
#include <hip/hip_runtime.h>
#include <hip/hip_bf16.h>

#define HH 448
#define WW 160
#define NPIX (HH*WW)

typedef unsigned long long u64;
typedef _Float16 h8 __attribute__((ext_vector_type(8)));
typedef _Float16 h4 __attribute__((ext_vector_type(4)));
typedef float f32x4 __attribute__((ext_vector_type(4)));

#define MFMA16(A,B,C) __builtin_amdgcn_mfma_f32_16x16x32_f16(A,B,C,0,0,0)
#define LO_SCALE 4096.0f
#define LO_INV   (1.0f/4096.0f)

__device__ __forceinline__ float leaky(float v) { return v >= 0.f ? v : 0.01f * v; }

__device__ __forceinline__ u64 packKey(float m, int r) {
    unsigned u = __float_as_uint(m);
    u = (u & 0x80000000u) ? ~u : (u | 0x80000000u);   // monotone f32 -> u32
    return ((u64)u << 32) | (unsigned)(255 - r);       // ties -> lowest idx
}

// split a fp32 into fp16 hi + scaled fp16 lo:  a ~= hi + lo*2^-12  (|err| <= 2^-24 |a|)
__device__ __forceinline__ _Float16 splitHi(float v) { return (_Float16)v; }
__device__ __forceinline__ _Float16 splitLo(float v, _Float16 hi) {
    return (_Float16)((v - (float)hi) * LO_SCALE);
}

__device__ __forceinline__ void cvtA(const float4& v0, const float4& v1, h8& ah, h8& al) {
    const float v[8] = {v0.x,v0.y,v0.z,v0.w,v1.x,v1.y,v1.z,v1.w};
#pragma unroll
    for (int j = 0; j < 8; ++j) {
        const _Float16 hi = splitHi(v[j]);
        ah[j] = hi;
        al[j] = splitLo(v[j], hi);
    }
}

// One pass: 2 row-tiles x 5 col-tiles of 16x16 out, K=128 (4 MFMA K-steps), 3-term split.
// A (weights): straight from global, lane l reads rows (tile + l&15), k = s*32+(l>>4)*8..+7
//   -> per instruction-pair the wave touches 16 full 128B lines (dense).
// B (activations): fp16-split pairs from LDS, one ds_read_b128 per frag.
__device__ __forceinline__ void gemmPass(const _Float16* lah, const _Float16* lal,
                                         const float* __restrict__ Wp,
                                         int lrow, int lg, int col0,
                                         f32x4 aH[2][5], f32x4 aL[2][5])
{
    const f32x4 zero = {0.f, 0.f, 0.f, 0.f};
#pragma unroll
    for (int i = 0; i < 2; ++i)
#pragma unroll
        for (int c = 0; c < 5; ++c) { aH[i][c] = zero; aL[i][c] = zero; }

    const float* wb0 = Wp + lrow * 128 + lg * 8;
    const float* wb1 = Wp + (16 + lrow) * 128 + lg * 8;
    float4 n00 = *(const float4*)(wb0);
    float4 n01 = *(const float4*)(wb0 + 4);
    float4 n10 = *(const float4*)(wb1);
    float4 n11 = *(const float4*)(wb1 + 4);

#pragma unroll 1
    for (int s = 0; s < 4; ++s) {
        const float4 c00 = n00, c01 = n01, c10 = n10, c11 = n11;
        if (s < 3) {                       // prefetch next K-step's raw weights
            n00 = *(const float4*)(wb0 + (s + 1) * 32);
            n01 = *(const float4*)(wb0 + (s + 1) * 32 + 4);
            n10 = *(const float4*)(wb1 + (s + 1) * 32);
            n11 = *(const float4*)(wb1 + (s + 1) * 32 + 4);
        }
        h8 Ah[2], Al[2];
        cvtA(c00, c01, Ah[0], Al[0]);
        cvtA(c10, c11, Ah[1], Al[1]);

        h8 Bh[5], Bl[5];
        const int gg = (s << 2) + lg;
#pragma unroll
        for (int c = 0; c < 5; ++c) {
            const int u = gg * 160 + col0 + (c << 4) + lrow;
            Bh[c] = *(const h8*)(lah + (u << 3));
            Bl[c] = *(const h8*)(lal + (u << 3));
        }
#pragma unroll
        for (int i = 0; i < 2; ++i)
#pragma unroll
            for (int c = 0; c < 5; ++c) {
                aH[i][c] = MFMA16(Ah[i], Bh[c], aH[i][c]);
                aL[i][c] = MFMA16(Ah[i], Bl[c], aL[i][c]);
                aL[i][c] = MFMA16(Al[i], Bh[c], aL[i][c]);
            }
    }
}

__global__ __launch_bounds__(512, 2) void kA(
    const float* __restrict__ x_in,
    const float* __restrict__ Wcl1, const float* __restrict__ bcl1,
    const float* __restrict__ Wcl2, const float* __restrict__ bcl2,
    const float* __restrict__ Wcl3, const float* __restrict__ bcl3,
    const float* __restrict__ Wcl4, const float* __restrict__ bcl4,
    const float* __restrict__ Wreg1, const float* __restrict__ breg1,
    __hip_bfloat16* __restrict__ xr, int* __restrict__ ind, float* __restrict__ out)
{
    __shared__ _Float16 lah[16 * 160 * 8];   // 40 KB: act hi, K-packed [g][col][8]
    __shared__ _Float16 lal[16 * 160 * 8];   // 40 KB: act lo*4096
    __shared__ u64 argb[160];

    const int h = blockIdx.x;
    const int t = threadIdx.x;
    const int wvid = t >> 6;
    const int l = t & 63;
    const int lrow = l & 15, lg = l >> 4;
    const int rtp = wvid >> 1;               // 0..3 row-tile pair
    const int ch = wvid & 1;                 // col half
    const int col0 = ch * 80;
    const int trb = rtp * 32;                // this wave's row base within a 128-row pass

    if (t < 160) argb[t] = 0ull;

    // ---- stage x: fp32 -> fp16-split pairs, K-packed ----
#pragma unroll 1
    for (int k = 0; k < 5; ++k) {
        const int id = t + (k << 9);         // 0..2559 = (g, col)
        const int g = id / 160, col = id - g * 160;
        float v[8];
#pragma unroll
        for (int j = 0; j < 8; ++j)
            v[j] = x_in[(size_t)(g * 8 + j) * 71680 + h * 160 + col];
        h8 hh, ll;
#pragma unroll
        for (int j = 0; j < 8; ++j) {
            const _Float16 hi = splitHi(v[j]);
            hh[j] = hi;
            ll[j] = splitLo(v[j], hi);
        }
        const int u = g * 160 + col;
        *(h8*)(lah + (u << 3)) = hh;
        *(h8*)(lal + (u << 3)) = ll;
    }
    __syncthreads();

    // ---- reg1: 256 rows in 2 passes, bf16 out to xr (no LDS writes) ----
    {
        const float* W1 = Wreg1 + (size_t)h * 32768;
        const float* b1 = breg1 + h * 256;
#pragma unroll 1
        for (int p = 0; p < 2; ++p) {
            const int rowOff = (p << 7) + trb;
            f32x4 aH[2][5], aL[2][5];
            gemmPass(lah, lal, W1 + rowOff * 128, lrow, lg, col0, aH, aL);
#pragma unroll
            for (int i = 0; i < 2; ++i) {
                const int r0 = rowOff + (i << 4) + (lg << 2);
                const float4 bb = *(const float4*)&b1[r0];
#pragma unroll
                for (int c = 0; c < 5; ++c) {
                    const int col = col0 + (c << 4) + lrow;
                    alignas(8) unsigned short us[4];
#pragma unroll
                    for (int r = 0; r < 4; ++r) {
                        const float a = aH[i][c][r] + aL[i][c][r] * LO_INV + ((const float*)&bb)[r];
                        __hip_bfloat16 bv = __float2bfloat16(leaky(a));
                        us[r] = *(const unsigned short*)&bv;
                    }
                    *(uint2*)(xr + (((size_t)(h * 160 + col)) << 8) + r0) = *(const uint2*)us;
                }
            }
        }
    }

    // ---- cl1..cl3: in-place act update (compute -> barrier -> write -> barrier) ----
#pragma unroll 1
    for (int L = 0; L < 3; ++L) {
        const float* W = (L == 0) ? Wcl1 + (size_t)h * 16384
                       : (L == 1) ? Wcl2 + (size_t)h * 16384
                                  : Wcl3 + (size_t)h * 16384;
        const float* b = (L == 0) ? bcl1 + (h << 7)
                       : (L == 1) ? bcl2 + (h << 7)
                                  : bcl3 + (h << 7);
        f32x4 aH[2][5], aL[2][5];
        gemmPass(lah, lal, W + trb * 128, lrow, lg, col0, aH, aL);
        float nv[2][5][4];
#pragma unroll
        for (int i = 0; i < 2; ++i) {
            const int r0 = trb + (i << 4) + (lg << 2);
            const float4 bb = *(const float4*)&b[r0];
#pragma unroll
            for (int c = 0; c < 5; ++c)
#pragma unroll
                for (int r = 0; r < 4; ++r)
                    nv[i][c][r] = leaky(aH[i][c][r] + aL[i][c][r] * LO_INV + ((const float*)&bb)[r]);
        }
        __syncthreads();                 // all reads of old act done
#pragma unroll
        for (int i = 0; i < 2; ++i) {
            const int r0 = trb + (i << 4) + (lg << 2);
            const int g = r0 >> 3, off = r0 & 7;
#pragma unroll
            for (int c = 0; c < 5; ++c) {
                const int col = col0 + (c << 4) + lrow;
                h4 wh, wl;
#pragma unroll
                for (int r = 0; r < 4; ++r) {
                    const _Float16 hi = splitHi(nv[i][c][r]);
                    wh[r] = hi;
                    wl[r] = splitLo(nv[i][c][r], hi);
                }
                *(h4*)(lah + ((g * 160 + col) << 3) + off) = wh;
                *(h4*)(lal + ((g * 160 + col) << 3) + off) = wl;
            }
        }
        __syncthreads();
    }

    // ---- cl4: 256 class rows in 2 passes; argmax only ----
    {
        const float* W4 = Wcl4 + (size_t)h * 32896;
        const float* b4 = bcl4 + h * 257;
        float mv[5]; int mr[5];
#pragma unroll
        for (int c = 0; c < 5; ++c) { mv[c] = -3.4e38f; mr[c] = 0; }
#pragma unroll 1
        for (int p = 0; p < 2; ++p) {
            const int rowOff = (p << 7) + trb;
            f32x4 aH[2][5], aL[2][5];
            gemmPass(lah, lal, W4 + rowOff * 128, lrow, lg, col0, aH, aL);
#pragma unroll
            for (int i = 0; i < 2; ++i) {
                const int r0 = rowOff + (i << 4) + (lg << 2);
                const float4 bb = *(const float4*)&b4[r0];
#pragma unroll
                for (int c = 0; c < 5; ++c)
#pragma unroll
                    for (int r = 0; r < 4; ++r) {
                        const float a = aH[i][c][r] + aL[i][c][r] * LO_INV + ((const float*)&bb)[r];
                        if (a > mv[c]) { mv[c] = a; mr[c] = r0 + r; }   // rows ascending per lane
                    }
            }
        }
#pragma unroll
        for (int c = 0; c < 5; ++c)
            atomicMax(&argb[col0 + (c << 4) + lrow], packKey(mv[c], mr[c]));
    }
    __syncthreads();

    // ---- finalize: ind + mask row (act holds cl3 output as split pairs) ----
    if (t < 160) {
        const u64 kk = argb[t];
        ind[h * 160 + t] = 255 - (int)(kk & 0xFFu);
        const float* Wm = Wcl4 + (size_t)h * 32896 + 32768;   // class row 256
        float accm = 0.f;
#pragma unroll 2
        for (int g = 0; g < 16; ++g) {
            const h8 hv = *(const h8*)(lah + ((g * 160 + t) << 3));
            const h8 lv = *(const h8*)(lal + ((g * 160 + t) << 3));
            const float4 w0 = *(const float4*)&Wm[g * 8];
            const float4 w1 = *(const float4*)&Wm[g * 8 + 4];
            const float wv[8] = {w0.x,w0.y,w0.z,w0.w,w1.x,w1.y,w1.z,w1.w};
#pragma unroll
            for (int j = 0; j < 8; ++j)
                accm = fmaf(wv[j], (float)hv[j] + (float)lv[j] * LO_INV, accm);
        }
        out[NPIX + h * 160 + t] = leaky(accm + bcl4[h * 257 + 256]);
    }
}

__global__ __launch_bounds__(256) void kB(
    const __hip_bfloat16* __restrict__ xr, const int* __restrict__ ind,
    const float* __restrict__ Wcm2, const float* __restrict__ bcm2,
    const float* __restrict__ Wcm3, const float* __restrict__ bcm3,
    float* __restrict__ out)
{
    const int gwave = (int)((blockIdx.x * blockDim.x + threadIdx.x) >> 6);
    const int lane = threadIdx.x & 63;
    const int nwave = (int)(gridDim.x * (blockDim.x >> 6));

    for (int n = gwave; n < NPIX; n += nwave) {
        const int h_o = n % HH, w_o = n / HH;   // xr source & output position (w-major flat)
        const int h_i = n / WW, w_i = n % WW;   // index-gather position (h-major flat)
        const int ig = ind[h_i * WW + w_i];
        const int sc = (ig >> 4) + (h_i << 4);
        const int rr = ig + (h_i << 8);

        const __hip_bfloat16* xp = xr + (size_t)(h_o * WW + w_o) * 256;
        const float* Wp = Wcm2 + (size_t)sc * 2048;

        float acc[8];
#pragma unroll
        for (int o = 0; o < 8; ++o) acc[o] = 0.f;

        const int c0 = lane * 4;
        const ushort4 xv4 = *(const ushort4*)((const unsigned short*)xp + c0);
        float xf[4];
        xf[0] = __uint_as_float((unsigned int)xv4.x << 16);
        xf[1] = __uint_as_float((unsigned int)xv4.y << 16);
        xf[2] = __uint_as_float((unsigned int)xv4.z << 16);
        xf[3] = __uint_as_float((unsigned int)xv4.w << 16);

#pragma unroll
        for (int i = 0; i < 4; ++i) {
            const float4* wrow = (const float4*)&Wp[(c0 + i) * 8];
            const float4 wa = wrow[0];
            const float4 wb_ = wrow[1];
            const float x = xf[i];
            acc[0] += x * wa.x;  acc[1] += x * wa.y;  acc[2] += x * wa.z;  acc[3] += x * wa.w;
            acc[4] += x * wb_.x; acc[5] += x * wb_.y; acc[6] += x * wb_.z; acc[7] += x * wb_.w;
        }
#pragma unroll
        for (int o = 0; o < 8; ++o) {
            float v = acc[o];
#pragma unroll
            for (int d = 32; d > 0; d >>= 1) v += __shfl_xor(v, d, 64);
            acc[o] = v;
        }
        float r = bcm3[rr];
        const float* b2 = bcm2 + (size_t)sc * 8;
        const float* w3 = Wcm3 + (size_t)rr * 8;
#pragma unroll
        for (int o = 0; o < 8; ++o) {
            const float y = leaky(acc[o] + b2[o]);
            r += y * w3[o];
        }
        if (lane == 0) {
            const float iv = (float)ind[h_o * WW + w_o];
            out[h_o * WW + w_o] = (iv + r) * (1.0f / 256.0f);
        }
    }
}

extern "C" void kernel_launch(void* const* d_in, const int* in_sizes, int n_in,
                              void* d_out, int out_size, void* d_ws, size_t ws_size,
                              hipStream_t stream)
{
    const float* x_in  = (const float*)d_in[0];
    const float* Wcl1  = (const float*)d_in[1];
    const float* bcl1  = (const float*)d_in[2];
    const float* Wcl2  = (const float*)d_in[3];
    const float* bcl2  = (const float*)d_in[4];
    const float* Wcl3  = (const float*)d_in[5];
    const float* bcl3  = (const float*)d_in[6];
    const float* Wcl4  = (const float*)d_in[7];
    const float* bcl4  = (const float*)d_in[8];
    const float* Wreg1 = (const float*)d_in[9];
    const float* breg1 = (const float*)d_in[10];
    const float* Wcm2  = (const float*)d_in[11];
    const float* bcm2  = (const float*)d_in[12];
    const float* Wcm3  = (const float*)d_in[13];
    const float* bcm3  = (const float*)d_in[14];

    float* out = (float*)d_out;

    // workspace: x_r as bf16 [448][160][256], then ind int32 [448*160]
    __hip_bfloat16* xr = (__hip_bfloat16*)d_ws;
    int* ind = (int*)((char*)d_ws + (size_t)NPIX * 256 * sizeof(__hip_bfloat16));

    kA<<<dim3(HH), dim3(512), 0, stream>>>(x_in, Wcl1, bcl1, Wcl2, bcl2, Wcl3, bcl3,
                                           Wcl4, bcl4, Wreg1, breg1, xr, ind, out);
    kB<<<dim3(1792), dim3(256), 0, stream>>>(xr, ind, Wcm2, bcm2, Wcm3, bcm3, out);
}